// Round 1
// 361.653 us; speedup vs baseline: 1.0912x; 1.0912x over previous
//
#include <hip/hip_runtime.h>
#include <hip/hip_fp16.h>
#include <stdint.h>

#define NN 50000
#define NE 800000
#define NG 256
#define NBUCKET 16
#define PARTSZ (NBUCKET * 256)

// bucketed CSR build params
#define NBKT 391      // node buckets of 128
#define ABLK 391
#define ASLICE 2048
#define BCAP 2560

__device__ __forceinline__ float bf2f(unsigned short u) {
    return __uint_as_float(((unsigned)u) << 16);
}
__device__ __forceinline__ unsigned short f2bf(float f) {
    unsigned b = __float_as_uint(f);
    return (unsigned short)((b + 0x7FFF + ((b >> 16) & 1)) >> 16);  // RNE
}
__device__ __forceinline__ unsigned short f2h(float f) {
    __half h = __float2half(f);
    return *(unsigned short*)&h;
}
__device__ __forceinline__ float h2f(unsigned short u) {
    __half h = *(__half*)&u;
    return __half2float(h);
}

#define AFF4(u, sc, sh) { u.x = fmaxf(sc.x*u.x+sh.x,0.f); u.y = fmaxf(sc.y*u.y+sh.y,0.f); \
                          u.z = fmaxf(sc.z*u.z+sh.z,0.f); u.w = fmaxf(sc.w*u.w+sh.w,0.f); }

// wave-parallel exclusive scan of totals[0..NBKT) into sbase[0..NBKT] (sbase[NBKT]=sum)
// caller must __syncthreads() afterwards; only lanes tid<64 participate.
__device__ __forceinline__ void scan_totals(const int* __restrict__ totals,
                                            int* __restrict__ sbase, int tid) {
    if (tid < 64) {
        const int C = (NBKT + 63) / 64;  // 7
        int tv[C];
        int s = 0;
        int i0 = tid * C;
#pragma unroll
        for (int j = 0; j < C; ++j) {
            int idx = i0 + j;
            int x = (idx < NBKT) ? totals[idx] : 0;
            tv[j] = x; s += x;
        }
        int inc = s;
        for (int off = 1; off < 64; off <<= 1) {
            int t2 = __shfl_up(inc, off, 64);
            if (tid >= off) inc += t2;
        }
        int run = inc - s;
#pragma unroll
        for (int j = 0; j < C; ++j) {
            int idx = i0 + j;
            if (idx < NBKT) sbase[idx] = run;
            run += tv[j];
        }
        if (tid == 63) sbase[NBKT] = run;
    }
}

// ---------------- prologue ----------------
__global__ void kA1(const int* __restrict__ col, int* __restrict__ bb, float* part, int e) {
    __shared__ int cnt[NBKT];
    for (int j = threadIdx.x; j < NBKT; j += 256) cnt[j] = 0;
    for (int i = blockIdx.x * 256 + threadIdx.x; i < 5 * PARTSZ; i += ABLK * 256) part[i] = 0.f;
    __syncthreads();
    int start = blockIdx.x * ASLICE;
    int end = min(start + ASLICE, e);
    for (int i = start + threadIdx.x; i < end; i += 256)
        atomicAdd(&cnt[col[i] >> 7], 1);
    __syncthreads();
    for (int j = threadIdx.x; j < NBKT; j += 256) bb[blockIdx.x * NBKT + j] = cnt[j];
}

// per-bucket exclusive scan of per-block counts; totals[k] = bucket-k edge count
__global__ void kA2a(int* __restrict__ bb, int* __restrict__ totals) {
    __shared__ int v[ABLK];
    int k = blockIdx.x;
    int tid = threadIdx.x;
    for (int b = tid; b < ABLK; b += 256) v[b] = bb[b * NBKT + k];
    __syncthreads();
    if (tid < 64) {
        const int C = (ABLK + 63) / 64;  // 7
        int tv[C];
        int s = 0;
        int i0 = tid * C;
#pragma unroll
        for (int j = 0; j < C; ++j) {
            int idx = i0 + j;
            int x = (idx < ABLK) ? v[idx] : 0;
            tv[j] = x; s += x;
        }
        int inc = s;
        for (int off = 1; off < 64; off <<= 1) {
            int t2 = __shfl_up(inc, off, 64);
            if (tid >= off) inc += t2;
        }
        int run = inc - s;
#pragma unroll
        for (int j = 0; j < C; ++j) {
            int idx = i0 + j;
            if (idx < ABLK) v[idx] = run;
            run += tv[j];
        }
        if (tid == 63) totals[k] = run;
    }
    __syncthreads();
    for (int b = tid; b < ABLK; b += 256) bb[b * NBKT + k] = v[b];
}

// A3 (blocks [0,ABLK)) + independent L1 gemm 128->16 (blocks [ABLK,..)) in one dispatch
// bucketbase is derived on the fly via wave-scan of totals (kA2b eliminated)
__global__ void kA3g(const int* __restrict__ row, const int* __restrict__ col,
                     const float* __restrict__ ew, const int* __restrict__ bb,
                     const int* __restrict__ totals, int2* __restrict__ staging,
                     const float* __restrict__ x, const float* __restrict__ W0,
                     float* __restrict__ m1, int e, int n) {
    __shared__ int cur[NBKT];
    __shared__ int sbase[NBKT + 1];
    __shared__ float Wl[128 * 16];
    int tid = threadIdx.x;
    if ((int)blockIdx.x < ABLK) {
        scan_totals(totals, sbase, tid);
        __syncthreads();
        for (int j = tid; j < NBKT; j += 256)
            cur[j] = sbase[j] + bb[blockIdx.x * NBKT + j];
        __syncthreads();
        int start = blockIdx.x * ASLICE;
        int end = min(start + ASLICE, e);
        for (int i = start + tid; i < end; i += 256) {
            int c = col[i];
            int p = atomicAdd(&cur[c >> 7], 1);
            staging[p] = make_int2(row[i] | ((c & 127) << 16), __float_as_int(ew[i]));
        }
        return;
    }
    int bid = (int)blockIdx.x - ABLK;
    for (int i = tid; i < 128 * 16 / 4; i += 256)
        ((float4*)Wl)[i] = ((const float4*)W0)[i];
    __syncthreads();
    int jq = tid % 4, group = tid / 4;
    int node0 = (bid * 64 + group) * 2;
    const float4* h4 = (const float4*)x;
    int hb[2]; bool val[2];
#pragma unroll
    for (int i = 0; i < 2; ++i) {
        int nd = node0 + i;
        val[i] = nd < n;
        hb[i] = (val[i] ? nd : n - 1) * 32;
    }
    float4 acc[2];
    acc[0] = {0,0,0,0}; acc[1] = {0,0,0,0};
#pragma unroll 4
    for (int k4 = 0; k4 < 32; ++k4) {
        const float* wb = &Wl[(k4 * 4) * 16 + jq * 4];
        float4 w0 = *(const float4*)(wb);
        float4 w1 = *(const float4*)(wb + 16);
        float4 w2 = *(const float4*)(wb + 32);
        float4 w3 = *(const float4*)(wb + 48);
#pragma unroll
        for (int i = 0; i < 2; ++i) {
            float4 hv = h4[hb[i] + k4];
            acc[i].x += hv.x*w0.x + hv.y*w1.x + hv.z*w2.x + hv.w*w3.x;
            acc[i].y += hv.x*w0.y + hv.y*w1.y + hv.z*w2.y + hv.w*w3.y;
            acc[i].z += hv.x*w0.z + hv.y*w1.z + hv.z*w2.z + hv.w*w3.z;
            acc[i].w += hv.x*w0.w + hv.y*w1.w + hv.z*w2.w + hv.w*w3.w;
        }
    }
#pragma unroll
    for (int i = 0; i < 2; ++i)
        if (val[i]) ((float4*)m1)[(node0 + i) * 4 + jq] = acc[i];
}

// csr entry: low16 = src node id (N<65536), high16 = fp16 weight
__global__ void __launch_bounds__(256) kB(const int* __restrict__ totals,
                                          const int2* __restrict__ staging,
                                          unsigned int* __restrict__ csr, int* __restrict__ ptr,
                                          float* __restrict__ dis, int n) {
    __shared__ int2 st[BCAP];
    __shared__ unsigned int outb[BCAP];
    __shared__ int hist[129];
    __shared__ int cur[128];
    __shared__ int sbase[NBKT + 1];
    int k = blockIdx.x, t = threadIdx.x;
    scan_totals(totals, sbase, t);
    if (t < 129) hist[t] = 0;
    __syncthreads();
    int base = sbase[k], cnt = sbase[k + 1] - sbase[k];
    int node0 = k << 7;
    int ncov = min(128, n - node0);
    if (cnt <= BCAP) {
        for (int i = t; i < cnt; i += 256) {
            int2 v = staging[base + i];
            st[i] = v;
            atomicAdd(&hist[v.x >> 16], 1);
        }
        __syncthreads();
        if (t == 0) {
            int run = 0;
            for (int j = 0; j < 128; ++j) { int h = hist[j]; hist[j] = run; run += h; }
            hist[128] = run;
        }
        __syncthreads();
        if (t < 128) cur[t] = hist[t];
        if (t < ncov) ptr[node0 + t] = base + hist[t];
        __syncthreads();
        for (int i = t; i < cnt; i += 256) {
            int2 v = st[i];
            int j = v.x >> 16;
            int p = atomicAdd(&cur[j], 1);
            outb[p] = (unsigned)(v.x & 0xFFFF) | ((unsigned)f2h(__int_as_float(v.y)) << 16);
        }
        __syncthreads();
        for (int i = t; i < cnt; i += 256) csr[base + i] = outb[i];
        if (t < ncov) {
            float s = 1.f;
            int a = hist[t], b2 = hist[t + 1];
            for (int p = a; p < b2; ++p) s += h2f((unsigned short)(outb[p] >> 16));
            dis[node0 + t] = rsqrtf(s);
        }
    } else {
        for (int i = t; i < cnt; i += 256) atomicAdd(&hist[staging[base + i].x >> 16], 1);
        __syncthreads();
        if (t == 0) {
            int run = 0;
            for (int j = 0; j < 128; ++j) { int h = hist[j]; hist[j] = run; run += h; }
            hist[128] = run;
        }
        __syncthreads();
        if (t < 128) cur[t] = hist[t];
        if (t < ncov) ptr[node0 + t] = base + hist[t];
        __syncthreads();
        for (int i = t; i < cnt; i += 256) {
            int2 v = staging[base + i];
            int j = v.x >> 16;
            int p = atomicAdd(&cur[j], 1);
            csr[base + p] = (unsigned)(v.x & 0xFFFF) | ((unsigned)f2h(__int_as_float(v.y)) << 16);
        }
        __threadfence_block();
        __syncthreads();
        if (t < ncov) {
            float s = 1.f;
            int a = hist[t], b2 = hist[t + 1];
            for (int p = a; p < b2; ++p) s += h2f((unsigned short)(csr[base + p] >> 16));
            dis[node0 + t] = rsqrtf(s);
        }
    }
    if (k == gridDim.x - 1 && t == 0) ptr[n] = sbase[NBKT];
}

// ---------------- L1 gather: EPI (bias+relu+stats) + CSR rescale write-back ----------------
__global__ void k_l1gather(const float* __restrict__ src, const int* __restrict__ ptr,
                           unsigned int* __restrict__ csr, const float* __restrict__ dis,
                           const float* __restrict__ bias, float* __restrict__ partOut,
                           float* __restrict__ out, int n) {
    __shared__ float ls[16], lq[16];
    int tid = threadIdx.x;
    if (tid < 16) { ls[tid] = 0.f; lq[tid] = 0.f; }
    __syncthreads();
    int t = blockIdx.x * 256 + tid;
    int node = t >> 2;
    int l4 = t & 3;
    bool valid = node < n;
    int nc = valid ? node : n - 1;
    const float4* s4 = (const float4*)src;
    float dc = dis[nc];
    float w0 = dc * dc;
    float4 v = s4[nc * 4 + l4];
    float4 acc = { w0 * v.x, w0 * v.y, w0 * v.z, w0 * v.w };
    int p0 = ptr[nc], p1 = ptr[nc + 1];
    int p = p0;
    for (; p + 4 <= p1; p += 4) {
        unsigned int c0 = csr[p], c1 = csr[p+1], c2 = csr[p+2], c3 = csr[p+3];
        int s0i = c0 & 0xFFFF, s1i = c1 & 0xFFFF, s2i = c2 & 0xFFFF, s3i = c3 & 0xFFFF;
        float e0 = dis[s0i] * h2f((unsigned short)(c0 >> 16)) * dc;
        float e1 = dis[s1i] * h2f((unsigned short)(c1 >> 16)) * dc;
        float e2 = dis[s2i] * h2f((unsigned short)(c2 >> 16)) * dc;
        float e3 = dis[s3i] * h2f((unsigned short)(c3 >> 16)) * dc;
        float4 u0 = s4[s0i * 4 + l4];
        float4 u1 = s4[s1i * 4 + l4];
        float4 u2 = s4[s2i * 4 + l4];
        float4 u3 = s4[s3i * 4 + l4];
        acc.x += e0*u0.x + e1*u1.x + e2*u2.x + e3*u3.x;
        acc.y += e0*u0.y + e1*u1.y + e2*u2.y + e3*u3.y;
        acc.z += e0*u0.z + e1*u1.z + e2*u2.z + e3*u3.z;
        acc.w += e0*u0.w + e1*u1.w + e2*u2.w + e3*u3.w;
        if (l4 == 0) {
            csr[p]   = (unsigned)s0i | ((unsigned)f2h(e0) << 16);
            csr[p+1] = (unsigned)s1i | ((unsigned)f2h(e1) << 16);
            csr[p+2] = (unsigned)s2i | ((unsigned)f2h(e2) << 16);
            csr[p+3] = (unsigned)s3i | ((unsigned)f2h(e3) << 16);
        }
    }
    for (; p < p1; ++p) {
        unsigned int ce = csr[p];
        int si = ce & 0xFFFF;
        float w = dis[si] * h2f((unsigned short)(ce >> 16)) * dc;
        float4 u = s4[si * 4 + l4];
        acc.x += w*u.x; acc.y += w*u.y; acc.z += w*u.z; acc.w += w*u.w;
        if (l4 == 0) csr[p] = (unsigned)si | ((unsigned)f2h(w) << 16);
    }
    float4 b = ((const float4*)bias)[l4];
    acc.x = fmaxf(acc.x + b.x, 0.f);
    acc.y = fmaxf(acc.y + b.y, 0.f);
    acc.z = fmaxf(acc.z + b.z, 0.f);
    acc.w = fmaxf(acc.w + b.w, 0.f);
    if (valid) ((float4*)out)[nc * 4 + l4] = acc;
    float s0 = valid ? acc.x : 0.f, s1 = valid ? acc.y : 0.f;
    float s2 = valid ? acc.z : 0.f, s3 = valid ? acc.w : 0.f;
    float q0 = s0*s0, q1 = s1*s1, q2 = s2*s2, q3 = s3*s3;
    for (int off = 4; off < 64; off <<= 1) {
        s0 += __shfl_down(s0, off, 64); s1 += __shfl_down(s1, off, 64);
        s2 += __shfl_down(s2, off, 64); s3 += __shfl_down(s3, off, 64);
        q0 += __shfl_down(q0, off, 64); q1 += __shfl_down(q1, off, 64);
        q2 += __shfl_down(q2, off, 64); q3 += __shfl_down(q3, off, 64);
    }
    int lane = tid & 63;
    if (lane < 4) {
        atomicAdd(&ls[4*lane+0], s0); atomicAdd(&ls[4*lane+1], s1);
        atomicAdd(&ls[4*lane+2], s2); atomicAdd(&ls[4*lane+3], s3);
        atomicAdd(&lq[4*lane+0], q0); atomicAdd(&lq[4*lane+1], q1);
        atomicAdd(&lq[4*lane+2], q2); atomicAdd(&lq[4*lane+3], q3);
    }
    __syncthreads();
    int bkt = (blockIdx.x & (NBUCKET - 1)) * 256;
    if (tid < 16) {
        atomicAdd(&partOut[bkt + tid], ls[tid]);
        atomicAdd(&partOut[bkt + 128 + tid], lq[tid]);
    }
}

// row loader: fp32 float4 or bf16 ushort4 -> float4
template <int D, int BF16>
__device__ __forceinline__ float4 load_row(const void* src, int node, int l4) {
    if (BF16) {
        const unsigned short* sb = (const unsigned short*)src;
        ushort4 r = *(const ushort4*)(sb + (size_t)node * D + (l4 << 2));
        float4 f;
        f.x = bf2f(r.x); f.y = bf2f(r.y); f.z = bf2f(r.z); f.w = bf2f(r.w);
        return f;
    } else {
        const float4* s4 = (const float4*)src;
        return s4[(size_t)node * (D / 4) + l4];
    }
}

// 16B-wide bf16 row loader: 8 bf16 per lane
template <int D>
__device__ __forceinline__ void ldrow16(const unsigned short* __restrict__ src, int node, int l8,
                                        float4& a, float4& b) {
    uint4 r = *(const uint4*)(src + (size_t)node * D + (l8 << 3));
    a.x = bf2f((unsigned short)(r.x)); a.y = bf2f((unsigned short)(r.x >> 16));
    a.z = bf2f((unsigned short)(r.y)); a.w = bf2f((unsigned short)(r.y >> 16));
    b.x = bf2f((unsigned short)(r.z)); b.y = bf2f((unsigned short)(r.z >> 16));
    b.z = bf2f((unsigned short)(r.w)); b.w = bf2f((unsigned short)(r.w >> 16));
}

// ---------------- fused layer (F2 only — 2KB Wl): gather -> LDS rows -> gemm ------------
template <int DIN, int DOUT, int EP, int POSTAFF, int PREAFF, int RELU,
          int BF16IN, int BF16OUT, int NPB>
__global__ void __launch_bounds__(256) k_fused(
        const void* __restrict__ src, const int* __restrict__ ptr,
        const unsigned int* __restrict__ csr, const float* __restrict__ dis,
        const float* __restrict__ partIn, const float* __restrict__ gmv,
        const float* __restrict__ btv, const float* __restrict__ W,
        const float* __restrict__ bias, float* __restrict__ partOut,
        void* __restrict__ out, int n) {
    const int TPN1 = DIN / 4, LPN = TPN1 * EP, GN1 = 256 / LPN;
    const int TPN2 = DOUT / 4, G2 = 256 / TPN2;
    const int HS = DIN + 4;
    __shared__ float Wl[DIN * DOUT];
    __shared__ float hrow[NPB * HS];
    __shared__ float scs[DIN], shs[DIN];
    __shared__ float ls[DOUT], lq[DOUT];
    int tid = threadIdx.x;
    for (int i = tid; i < DIN * DOUT / 4; i += 256)
        ((float4*)Wl)[i] = ((const float4*)W)[i];
    if (tid < DIN) {
        float s = 0.f, q = 0.f;
#pragma unroll
        for (int b2 = 0; b2 < NBUCKET; ++b2) {
            s += partIn[b2 * 256 + tid];
            q += partIn[b2 * 256 + 128 + tid];
        }
        float mu = s / (float)n;
        float var = q / (float)n - mu * mu;
        float a = gmv[tid] * rsqrtf(var + 1e-5f);
        scs[tid] = a;
        shs[tid] = btv[tid] - mu * a;
    }
    if (tid < DOUT) { ls[tid] = 0.f; lq[tid] = 0.f; }
    __syncthreads();

    int nodebase = blockIdx.x * NPB;
    {
        int grp = tid / LPN, r = tid % LPN;
        int e0 = r / TPN1, l4 = r % TPN1;
        float4 sc = ((const float4*)scs)[l4];
        float4 sh = ((const float4*)shs)[l4];
#pragma unroll
        for (int pass = 0; pass < NPB / GN1; ++pass) {
            int nl = pass * GN1 + grp;
            int node = nodebase + nl;
            int nc = node < n ? node : n - 1;
            float4 acc = {0.f, 0.f, 0.f, 0.f};
            float sumw = 0.f;
            if (e0 == 0) {
                float d = dis[nc];
                float w0 = d * d;
                float4 v = load_row<DIN, BF16IN>(src, nc, l4);
                if (PREAFF) AFF4(v, sc, sh);
                acc.x = w0*v.x; acc.y = w0*v.y; acc.z = w0*v.z; acc.w = w0*v.w;
                sumw = w0;
            }
            int p0 = ptr[nc], p1 = ptr[nc + 1];
            int p = p0 + e0;
            for (; p + 3 * EP < p1; p += 4 * EP) {
                unsigned int c0 = csr[p], c1 = csr[p + EP], c2 = csr[p + 2*EP], c3 = csr[p + 3*EP];
                float e0w = h2f((unsigned short)(c0 >> 16)), e1w = h2f((unsigned short)(c1 >> 16));
                float e2w = h2f((unsigned short)(c2 >> 16)), e3w = h2f((unsigned short)(c3 >> 16));
                float4 u0 = load_row<DIN, BF16IN>(src, c0 & 0xFFFF, l4);
                float4 u1 = load_row<DIN, BF16IN>(src, c1 & 0xFFFF, l4);
                float4 u2 = load_row<DIN, BF16IN>(src, c2 & 0xFFFF, l4);
                float4 u3 = load_row<DIN, BF16IN>(src, c3 & 0xFFFF, l4);
                if (PREAFF) { AFF4(u0, sc, sh); AFF4(u1, sc, sh); AFF4(u2, sc, sh); AFF4(u3, sc, sh); }
                acc.x += e0w*u0.x + e1w*u1.x + e2w*u2.x + e3w*u3.x;
                acc.y += e0w*u0.y + e1w*u1.y + e2w*u2.y + e3w*u3.y;
                acc.z += e0w*u0.z + e1w*u1.z + e2w*u2.z + e3w*u3.z;
                acc.w += e0w*u0.w + e1w*u1.w + e2w*u2.w + e3w*u3.w;
                if (POSTAFF) sumw += e0w + e1w + e2w + e3w;
            }
            for (; p < p1; p += EP) {
                unsigned int ce = csr[p];
                float w = h2f((unsigned short)(ce >> 16));
                float4 u = load_row<DIN, BF16IN>(src, ce & 0xFFFF, l4);
                if (PREAFF) AFF4(u, sc, sh);
                acc.x += w*u.x; acc.y += w*u.y; acc.z += w*u.z; acc.w += w*u.w;
                if (POSTAFF) sumw += w;
            }
#pragma unroll
            for (int off = TPN1; off < LPN; off <<= 1) {
                acc.x += __shfl_xor(acc.x, off, 64);
                acc.y += __shfl_xor(acc.y, off, 64);
                acc.z += __shfl_xor(acc.z, off, 64);
                acc.w += __shfl_xor(acc.w, off, 64);
                if (POSTAFF) sumw += __shfl_xor(sumw, off, 64);
            }
            if (POSTAFF) {
                acc.x = sc.x * acc.x + sh.x * sumw;
                acc.y = sc.y * acc.y + sh.y * sumw;
                acc.z = sc.z * acc.z + sh.z * sumw;
                acc.w = sc.w * acc.w + sh.w * sumw;
            }
            if (e0 == 0) *(float4*)&hrow[nl * HS + (l4 << 2)] = acc;
        }
    }
    __syncthreads();
    {
        int jq = tid % TPN2, g2 = tid / TPN2;
        float4 bv = ((const float4*)bias)[jq];
        float4 sv = {0,0,0,0}, qv = {0,0,0,0};
        for (int nl = g2; nl < NPB; nl += G2) {
            int node = nodebase + nl;
            bool valid = node < n;
            float4 a = {0.f, 0.f, 0.f, 0.f};
#pragma unroll
            for (int k4 = 0; k4 < DIN / 4; ++k4) {
                float4 hv = *(const float4*)&hrow[nl * HS + (k4 << 2)];
                const float* wb = &Wl[(k4 * 4) * DOUT + jq * 4];
                float4 w0 = *(const float4*)(wb);
                float4 w1 = *(const float4*)(wb + DOUT);
                float4 w2 = *(const float4*)(wb + 2 * DOUT);
                float4 w3 = *(const float4*)(wb + 3 * DOUT);
                a.x += hv.x*w0.x + hv.y*w1.x + hv.z*w2.x + hv.w*w3.x;
                a.y += hv.x*w0.y + hv.y*w1.y + hv.z*w2.y + hv.w*w3.y;
                a.z += hv.x*w0.z + hv.y*w1.z + hv.z*w2.z + hv.w*w3.z;
                a.w += hv.x*w0.w + hv.y*w1.w + hv.z*w2.w + hv.w*w3.w;
            }
            a.x += bv.x; a.y += bv.y; a.z += bv.z; a.w += bv.w;
            if (RELU) {
                a.x = fmaxf(a.x, 0.f); a.y = fmaxf(a.y, 0.f);
                a.z = fmaxf(a.z, 0.f); a.w = fmaxf(a.w, 0.f);
            }
            if (valid) {
                if (BF16OUT) {
                    ushort4 o;
                    o.x = f2bf(a.x); o.y = f2bf(a.y); o.z = f2bf(a.z); o.w = f2bf(a.w);
                    *(ushort4*)((unsigned short*)out + (size_t)node * DOUT + (jq << 2)) = o;
                } else {
                    ((float4*)out)[(size_t)node * TPN2 + jq] = a;
                }
                sv.x += a.x; sv.y += a.y; sv.z += a.z; sv.w += a.w;
                qv.x += a.x*a.x; qv.y += a.y*a.y; qv.z += a.z*a.z; qv.w += a.w*a.w;
            }
        }
        for (int off = TPN2; off < 64; off <<= 1) {
            sv.x += __shfl_down(sv.x, off, 64); sv.y += __shfl_down(sv.y, off, 64);
            sv.z += __shfl_down(sv.z, off, 64); sv.w += __shfl_down(sv.w, off, 64);
            qv.x += __shfl_down(qv.x, off, 64); qv.y += __shfl_down(qv.y, off, 64);
            qv.z += __shfl_down(qv.z, off, 64); qv.w += __shfl_down(qv.w, off, 64);
        }
        int lane = tid & 63;
        if (lane < TPN2) {
            atomicAdd(&ls[4*lane+0], sv.x); atomicAdd(&ls[4*lane+1], sv.y);
            atomicAdd(&ls[4*lane+2], sv.z); atomicAdd(&ls[4*lane+3], sv.w);
            atomicAdd(&lq[4*lane+0], qv.x); atomicAdd(&lq[4*lane+1], qv.y);
            atomicAdd(&lq[4*lane+2], qv.z); atomicAdd(&lq[4*lane+3], qv.w);
        }
        __syncthreads();
        int bkt = (blockIdx.x & (NBUCKET - 1)) * 256;
        if (tid < DOUT) {
            atomicAdd(&partOut[bkt + tid], ls[tid]);
            atomicAdd(&partOut[bkt + 128 + tid], lq[tid]);
        }
    }
}

// ---------------- wide standalone gather (L3/L4/L5): 16B bf16 loads, EP=4, fp32-out -----
// POSTAFF: BN hoisted out of edge loop; PREAFF: per-edge relu(BN)
template <int D, int POSTAFF, int PREAFF>
__global__ void __launch_bounds__(256) k_wgather(
        const unsigned short* __restrict__ src, const int* __restrict__ ptr,
        const unsigned int* __restrict__ csr, const float* __restrict__ dis,
        const float* __restrict__ partIn, const float* __restrict__ gmv,
        const float* __restrict__ btv, float* __restrict__ out, int n) {
    const int RL = D / 8;          // lanes per 16B-row-chunk
    const int EP = 4;
    const int LPN = RL * EP;
    __shared__ float scs[D], shs[D];
    int tid = threadIdx.x;
    if (tid < D) {
        float s = 0.f, q = 0.f;
#pragma unroll
        for (int b2 = 0; b2 < NBUCKET; ++b2) {
            s += partIn[b2 * 256 + tid];
            q += partIn[b2 * 256 + 128 + tid];
        }
        float mu = s / (float)n;
        float var = q / (float)n - mu * mu;
        float a = gmv[tid] * rsqrtf(var + 1e-5f);
        scs[tid] = a;
        shs[tid] = btv[tid] - mu * a;
    }
    __syncthreads();
    int t = blockIdx.x * 256 + tid;
    int node = t / LPN;
    int r = t - node * LPN;
    int e0 = r / RL;
    int l8 = r - e0 * RL;
    bool valid = node < n;
    int nc = valid ? node : n - 1;
    float4 scA = ((const float4*)scs)[l8 * 2],     shA = ((const float4*)shs)[l8 * 2];
    float4 scB = ((const float4*)scs)[l8 * 2 + 1], shB = ((const float4*)shs)[l8 * 2 + 1];
    float4 accA = {0.f,0.f,0.f,0.f}, accB = {0.f,0.f,0.f,0.f};
    float sumw = 0.f;
    if (e0 == 0) {
        float d = dis[nc];
        float w0 = d * d;
        float4 a, b2;
        ldrow16<D>(src, nc, l8, a, b2);
        if (PREAFF) { AFF4(a, scA, shA); AFF4(b2, scB, shB); }
        accA.x = w0*a.x;  accA.y = w0*a.y;  accA.z = w0*a.z;  accA.w = w0*a.w;
        accB.x = w0*b2.x; accB.y = w0*b2.y; accB.z = w0*b2.z; accB.w = w0*b2.w;
        sumw = w0;
    }
    int p0 = ptr[nc], p1 = ptr[nc + 1];
    int p = p0 + e0;
    for (; p + 3 * EP < p1; p += 4 * EP) {
        unsigned int c0 = csr[p], c1 = csr[p + EP], c2 = csr[p + 2*EP], c3 = csr[p + 3*EP];
        float w0 = h2f((unsigned short)(c0 >> 16)), w1 = h2f((unsigned short)(c1 >> 16));
        float w2 = h2f((unsigned short)(c2 >> 16)), w3 = h2f((unsigned short)(c3 >> 16));
        float4 a0, b0, a1, b1, a2, b2, a3, b3;
        ldrow16<D>(src, c0 & 0xFFFF, l8, a0, b0);
        ldrow16<D>(src, c1 & 0xFFFF, l8, a1, b1);
        ldrow16<D>(src, c2 & 0xFFFF, l8, a2, b2);
        ldrow16<D>(src, c3 & 0xFFFF, l8, a3, b3);
        if (PREAFF) {
            AFF4(a0, scA, shA); AFF4(b0, scB, shB);
            AFF4(a1, scA, shA); AFF4(b1, scB, shB);
            AFF4(a2, scA, shA); AFF4(b2, scB, shB);
            AFF4(a3, scA, shA); AFF4(b3, scB, shB);
        }
        accA.x += w0*a0.x + w1*a1.x + w2*a2.x + w3*a3.x;
        accA.y += w0*a0.y + w1*a1.y + w2*a2.y + w3*a3.y;
        accA.z += w0*a0.z + w1*a1.z + w2*a2.z + w3*a3.z;
        accA.w += w0*a0.w + w1*a1.w + w2*a2.w + w3*a3.w;
        accB.x += w0*b0.x + w1*b1.x + w2*b2.x + w3*b3.x;
        accB.y += w0*b0.y + w1*b1.y + w2*b2.y + w3*b3.y;
        accB.z += w0*b0.z + w1*b1.z + w2*b2.z + w3*b3.z;
        accB.w += w0*b0.w + w1*b1.w + w2*b2.w + w3*b3.w;
        if (POSTAFF) sumw += w0 + w1 + w2 + w3;
    }
    for (; p < p1; p += EP) {
        unsigned int ce = csr[p];
        float w = h2f((unsigned short)(ce >> 16));
        float4 a, b2;
        ldrow16<D>(src, ce & 0xFFFF, l8, a, b2);
        if (PREAFF) { AFF4(a, scA, shA); AFF4(b2, scB, shB); }
        accA.x += w*a.x;  accA.y += w*a.y;  accA.z += w*a.z;  accA.w += w*a.w;
        accB.x += w*b2.x; accB.y += w*b2.y; accB.z += w*b2.z; accB.w += w*b2.w;
        if (POSTAFF) sumw += w;
    }
#pragma unroll
    for (int off = RL; off < LPN; off <<= 1) {
        accA.x += __shfl_xor(accA.x, off, 64); accA.y += __shfl_xor(accA.y, off, 64);
        accA.z += __shfl_xor(accA.z, off, 64); accA.w += __shfl_xor(accA.w, off, 64);
        accB.x += __shfl_xor(accB.x, off, 64); accB.y += __shfl_xor(accB.y, off, 64);
        accB.z += __shfl_xor(accB.z, off, 64); accB.w += __shfl_xor(accB.w, off, 64);
        if (POSTAFF) sumw += __shfl_xor(sumw, off, 64);
    }
    if (POSTAFF) {
        accA.x = scA.x * accA.x + shA.x * sumw; accA.y = scA.y * accA.y + shA.y * sumw;
        accA.z = scA.z * accA.z + shA.z * sumw; accA.w = scA.w * accA.w + shA.w * sumw;
        accB.x = scB.x * accB.x + shB.x * sumw; accB.y = scB.y * accB.y + shB.y * sumw;
        accB.z = scB.z * accB.z + shB.z * sumw; accB.w = scB.w * accB.w + shB.w * sumw;
    }
    if (valid && e0 == 0) {
        ((float4*)out)[(size_t)nc * (D / 4) + l8 * 2]     = accA;
        ((float4*)out)[(size_t)nc * (D / 4) + l8 * 2 + 1] = accB;
    }
}

// ---------------- standalone gemm DIN -> DOUT, bias + optional relu + stats ----------------
template <int DIN, int DOUT, int RELU, int BF16OUT>
__global__ void k_sgemm(const float* __restrict__ h, const float* __restrict__ W,
                        const float* __restrict__ bias, float* __restrict__ partOut,
                        void* __restrict__ m, int n) {
    const int TPN = DOUT / 4, GPB = 256 / TPN, NPT = 4;
    __shared__ float Wl[DIN * DOUT];
    __shared__ float ls[DOUT], lq[DOUT];
    int tid = threadIdx.x;
    for (int i = tid; i < DIN * DOUT / 4; i += 256)
        ((float4*)Wl)[i] = ((const float4*)W)[i];
    if (tid < DOUT) { ls[tid] = 0.f; lq[tid] = 0.f; }
    __syncthreads();

    int jq = tid % TPN;
    int group = tid / TPN;
    int node0 = (blockIdx.x * GPB + group) * NPT;
    const float4* h4 = (const float4*)h;
    int hb[NPT]; bool val[NPT];
#pragma unroll
    for (int i = 0; i < NPT; ++i) {
        int nd = node0 + i;
        val[i] = nd < n;
        hb[i] = (val[i] ? nd : n - 1) * (DIN / 4);
    }
    float4 acc[NPT];
#pragma unroll
    for (int i = 0; i < NPT; ++i) acc[i] = {0.f, 0.f, 0.f, 0.f};
#pragma unroll 4
    for (int k4 = 0; k4 < DIN / 4; ++k4) {
        const float* wb = &Wl[(k4 * 4) * DOUT + jq * 4];
        float4 w0 = *(const float4*)(wb);
        float4 w1 = *(const float4*)(wb + DOUT);
        float4 w2 = *(const float4*)(wb + 2 * DOUT);
        float4 w3 = *(const float4*)(wb + 3 * DOUT);
#pragma unroll
        for (int i = 0; i < NPT; ++i) {
            float4 hv = h4[hb[i] + k4];
            acc[i].x += hv.x*w0.x + hv.y*w1.x + hv.z*w2.x + hv.w*w3.x;
            acc[i].y += hv.x*w0.y + hv.y*w1.y + hv.z*w2.y + hv.w*w3.y;
            acc[i].z += hv.x*w0.z + hv.y*w1.z + hv.z*w2.z + hv.w*w3.z;
            acc[i].w += hv.x*w0.w + hv.y*w1.w + hv.z*w2.w + hv.w*w3.w;
        }
    }
    float4 bv = ((const float4*)bias)[jq];
    float4 sv = {0,0,0,0}, qv = {0,0,0,0};
#pragma unroll
    for (int i = 0; i < NPT; ++i) {
        float4 a = acc[i];
        a.x += bv.x; a.y += bv.y; a.z += bv.z; a.w += bv.w;
        if (RELU) {
            a.x = fmaxf(a.x, 0.f); a.y = fmaxf(a.y, 0.f);
            a.z = fmaxf(a.z, 0.f); a.w = fmaxf(a.w, 0.f);
        }
        if (val[i]) {
            if (BF16OUT) {
                ushort4 o;
                o.x = f2bf(a.x); o.y = f2bf(a.y); o.z = f2bf(a.z); o.w = f2bf(a.w);
                *(ushort4*)((unsigned short*)m + (size_t)(node0 + i) * DOUT + (jq << 2)) = o;
            } else {
                ((float4*)m)[(size_t)(node0 + i) * TPN + jq] = a;
            }
            sv.x += a.x; sv.y += a.y; sv.z += a.z; sv.w += a.w;
            qv.x += a.x*a.x; qv.y += a.y*a.y; qv.z += a.z*a.z; qv.w += a.w*a.w;
        }
    }
    for (int off = TPN; off < 64; off <<= 1) {
        sv.x += __shfl_down(sv.x, off, 64); sv.y += __shfl_down(sv.y, off, 64);
        sv.z += __shfl_down(sv.z, off, 64); sv.w += __shfl_down(sv.w, off, 64);
        qv.x += __shfl_down(qv.x, off, 64); qv.y += __shfl_down(qv.y, off, 64);
        qv.z += __shfl_down(qv.z, off, 64); qv.w += __shfl_down(qv.w, off, 64);
    }
    int lane = tid & 63;
    if (lane < TPN) {
        atomicAdd(&ls[4*lane+0], sv.x); atomicAdd(&ls[4*lane+1], sv.y);
        atomicAdd(&ls[4*lane+2], sv.z); atomicAdd(&ls[4*lane+3], sv.w);
        atomicAdd(&lq[4*lane+0], qv.x); atomicAdd(&lq[4*lane+1], qv.y);
        atomicAdd(&lq[4*lane+2], qv.z); atomicAdd(&lq[4*lane+3], qv.w);
    }
    __syncthreads();
    int bkt = (blockIdx.x & (NBUCKET - 1)) * 256;
    if (tid < DOUT) {
        atomicAdd(&partOut[bkt + tid], ls[tid]);
        atomicAdd(&partOut[bkt + 128 + tid], lq[tid]);
    }
}

// ---------------- fused pool (BN5 consumed inline) + MLP head ----------------
__global__ void k_poolhead(const float* __restrict__ h, const int* __restrict__ batch,
                           const float* __restrict__ partIn, const float* __restrict__ gmv,
                           const float* __restrict__ btv,
                           const float* __restrict__ fc1w, const float* __restrict__ fc1b,
                           const float* __restrict__ fc2w, const float* __restrict__ fc2b,
                           float* __restrict__ out, int n) {
    __shared__ float tmp[256];
    __shared__ float pl[128];
    __shared__ float scs[128], shs[128];
    int g = blockIdx.x;
    int tid = threadIdx.x;
    if (tid < 128) {
        float s = 0.f, q = 0.f;
#pragma unroll
        for (int b2 = 0; b2 < NBUCKET; ++b2) {
            s += partIn[b2 * 256 + tid];
            q += partIn[b2 * 256 + 128 + tid];
        }
        float mu = s / (float)n;
        float var = q / (float)n - mu * mu;
        float a = gmv[tid] * rsqrtf(var + 1e-5f);
        scs[tid] = a;
        shs[tid] = btv[tid] - mu * a;
    }
    int j = tid & 127, prt = tid >> 7;
    int a = 0, b = n;
    while (a < b) { int mid = (a + b) >> 1; if (batch[mid] < g) a = mid + 1; else b = mid; }
    int lo = a;
    b = n;
    while (a < b) { int mid = (a + b) >> 1; if (batch[mid] < g + 1) a = mid + 1; else b = mid; }
    int hi = a;

    float acc = 0.f;
    for (int node = lo + prt; node < hi; node += 2) acc += h[(long)node * 128 + j];
    tmp[tid] = acc;
    __syncthreads();
    if (tid < 128) {
        float cnt = (float)(hi - lo);
        float p = scs[tid] * (tmp[tid] + tmp[tid + 128]) + shs[tid] * cnt;
        pl[tid] = fmaxf(p, 0.f);
    }
    __syncthreads();
    if (tid < 64) {
        float v1 = fc1b[tid];
        for (int k = 0; k < 128; ++k) v1 += pl[k] * fc1w[k * 64 + tid];
        v1 = fmaxf(v1, 0.f);
        float v = v1 * fc2w[tid];
        for (int off = 32; off > 0; off >>= 1) v += __shfl_down(v, off, 64);
        if (tid == 0) out[g] = v + fc2b[0];
    }
}

// ---------------- driver ----------------
extern "C" void kernel_launch(void* const* d_in, const int* in_sizes, int n_in,
                              void* d_out, int out_size, void* d_ws, size_t ws_size,
                              hipStream_t stream) {
    const float* x     = (const float*)d_in[0];
    const int*   ei    = (const int*)d_in[1];
    const float* ew    = (const float*)d_in[2];
    const int*   batch = (const int*)d_in[3];
    const float *W[5], *b[5], *gm[5], *bt[5];
    for (int i = 0; i < 5; ++i) {
        W[i]  = (const float*)d_in[4 + 4 * i];
        b[i]  = (const float*)d_in[5 + 4 * i];
        gm[i] = (const float*)d_in[6 + 4 * i];
        bt[i] = (const float*)d_in[7 + 4 * i];
    }
    const float* fc1w = (const float*)d_in[24];
    const float* fc1b = (const float*)d_in[25];
    const float* fc2w = (const float*)d_in[26];
    const float* fc2b = (const float*)d_in[27];
    float* out = (float*)d_out;

    // workspace layout
    char* wsb = (char*)d_ws;
    float* dis    = (float*)wsb;  wsb += sizeof(float) * NN;
    int*   ptr    = (int*)wsb;    wsb += sizeof(int) * (NN + 4);
    int*   bb     = (int*)wsb;    wsb += sizeof(int) * ABLK * NBKT;
    int*   totals = (int*)wsb;    wsb += sizeof(int) * (NBKT + 1);
    wsb = (char*)(((uintptr_t)wsb + 15) & ~(uintptr_t)15);
    int2*  staging= (int2*)wsb;   wsb += sizeof(int2) * NE;
    unsigned int* csru = (unsigned int*)wsb; wsb += sizeof(unsigned int) * NE;
    wsb = (char*)(((uintptr_t)wsb + 15) & ~(uintptr_t)15);
    float* part   = (float*)wsb;  wsb += sizeof(float) * 5 * PARTSZ;
    unsigned short* bufB1 = (unsigned short*)wsb;  wsb += sizeof(unsigned short) * (size_t)NN * 64;
    unsigned short* bufB2 = (unsigned short*)wsb;  wsb += sizeof(unsigned short) * (size_t)NN * 64;
    float* buf1   = (float*)wsb;  wsb += sizeof(float) * (size_t)NN * 64;   // L1 m / agg scratch
    float* buf2   = (float*)wsb;  wsb += sizeof(float) * (size_t)NN * 128;

    const int* row = ei;
    const int* col = ei + NE;
    const int B = 256;
    const int NBF = (NN + 15) / 16;   // fused F2 blocks
    const int GB1 = (NN + 127) / 128; // gemm1 blocks

    // prologue: bucketed CSR build; gemm1 overlapped with kA3 (independent work)
    kA1<<<ABLK, B, 0, stream>>>(col, bb, part, NE);
    kA2a<<<NBKT, B, 0, stream>>>(bb, totals);
    kA3g<<<ABLK + GB1, B, 0, stream>>>(row, col, ew, bb, totals, staging, x, W[0], buf1, NE, NN);
    kB<<<NBKT, B, 0, stream>>>(totals, staging, csru, ptr, dis, NN);

    // L1 gather: bias+relu+stats (+ CSR rescale write-back, packed u16|f16)
    k_l1gather<<<(NN * 4 + 255) / 256, B, 0, stream>>>(buf1, ptr, csru, dis,
                                                       b[0], part + 0 * PARTSZ, buf2, NN);

    // F2: 16->32 fused (2KB Wl), consume part[0], fp32 in, bf16 out
    k_fused<16, 32, 4, 1, 0, 1, 0, 1, 16><<<NBF, B, 0, stream>>>(
        buf2, ptr, csru, dis, part + 0 * PARTSZ, gm[0], bt[0],
        W[1], b[1], part + 1 * PARTSZ, bufB1, NN);

    // L3: wide gather32 (BN2 hoisted) then gemm 32->64
    k_wgather<32, 1, 0><<<(int)(((long)NN * 16 + 255) / 256), B, 0, stream>>>(
        bufB1, ptr, csru, dis, part + 1 * PARTSZ, gm[1], bt[1], buf1, NN);
    k_sgemm<32, 64, 1, 1><<<(NN + 63) / 64, B, 0, stream>>>(buf1, W[2], b[2], part + 2 * PARTSZ, bufB2, NN);

    // L4: wide gather64 (BN3 hoisted) then gemm 64->64
    k_wgather<64, 1, 0><<<(int)(((long)NN * 32 + 255) / 256), B, 0, stream>>>(
        bufB2, ptr, csru, dis, part + 2 * PARTSZ, gm[2], bt[2], buf1, NN);
    k_sgemm<64, 64, 0, 1><<<(NN + 63) / 64, B, 0, stream>>>(buf1, W[3], b[3], part + 3 * PARTSZ, bufB1, NN);

    // L5: wide gather64 (per-edge relu(BN4)) then gemm 64->128
    k_wgather<64, 0, 1><<<(int)(((long)NN * 32 + 255) / 256), B, 0, stream>>>(
        bufB1, ptr, csru, dis, part + 3 * PARTSZ, gm[3], bt[3], buf1, NN);
    k_sgemm<64, 128, 0, 0><<<(NN + 31) / 32, B, 0, stream>>>(buf1, W[4], b[4], part + 4 * PARTSZ, buf2, NN);

    // fused pool (consume part[4] -> BN5) + head
    k_poolhead<<<NG, B, 0, stream>>>(buf2, batch, part + 4 * PARTSZ, gm[4], bt[4],
                                     fc1w, fc1b, fc2w, fc2b, out, NN);
}